// Round 1
// baseline (437.227 us; speedup 1.0000x reference)
//
#include <hip/hip_runtime.h>

#define SINKHORN_ITERS 20
#define N_STREAMS 4
#define DDIM 1024

// Kernel 1: sinkhorn on the 4x4 H_raw -> H (16 floats in d_ws).
// Work is ~1.3k flops; one thread does it serially. Launched as one wave.
__global__ void sinkhorn_k(const float* __restrict__ H_raw, float* __restrict__ H) {
    if (blockIdx.x == 0 && threadIdx.x == 0) {
        float A[4][4];
#pragma unroll
        for (int i = 0; i < 4; ++i)
#pragma unroll
            for (int j = 0; j < 4; ++j)
                A[i][j] = fabsf(H_raw[i * 4 + j]) + 1e-8f;

        for (int it = 0; it < SINKHORN_ITERS; ++it) {
            // row normalize (axis=1)
#pragma unroll
            for (int i = 0; i < 4; ++i) {
                float r = A[i][0] + A[i][1] + A[i][2] + A[i][3];
                float rinv = 1.0f / r;
#pragma unroll
                for (int j = 0; j < 4; ++j) A[i][j] *= rinv;
            }
            // col normalize (axis=0)
#pragma unroll
            for (int j = 0; j < 4; ++j) {
                float c = A[0][j] + A[1][j] + A[2][j] + A[3][j];
                float cinv = 1.0f / c;
#pragma unroll
                for (int i = 0; i < 4; ++i) A[i][j] *= cinv;
            }
        }
#pragma unroll
        for (int i = 0; i < 4; ++i)
#pragma unroll
            for (int j = 0; j < 4; ++j)
                H[i * 4 + j] = A[i][j];
    }
}

// Kernel 2: out[bt, n, d] = sum_m H[n][m] * x[bt, m, d]
// One thread per (bt, d/4): loads 4 float4 (one per stream m), writes 4 float4.
// Consecutive threads -> consecutive float4 within a 4 KiB stream chunk: fully
// coalesced 1 KiB/wave per vector-mem instruction.
__global__ __launch_bounds__(256) void mix_k(const float* __restrict__ x,
                                             const float* __restrict__ H,
                                             float* __restrict__ out,
                                             int n_items /* = BT * D/4 */) {
    int idx = blockIdx.x * 256 + threadIdx.x;
    if (idx >= n_items) return;
    int bt = idx >> 8;          // / (DDIM/4 = 256)
    int dv = idx & 255;         // float4 index within a stream chunk

    const float4* xp = (const float4*)(x) + (size_t)bt * (N_STREAMS * DDIM / 4) + dv;
    float4* op = (float4*)(out) + (size_t)bt * (N_STREAMS * DDIM / 4) + dv;

    // H is 16 floats, uniform address -> scalar loads, L2-broadcast.
    float h[16];
#pragma unroll
    for (int i = 0; i < 16; ++i) h[i] = H[i];

    const int C = DDIM / 4;  // 256 float4 per stream chunk
    float4 x0 = xp[0 * C];
    float4 x1 = xp[1 * C];
    float4 x2 = xp[2 * C];
    float4 x3 = xp[3 * C];

#pragma unroll
    for (int n = 0; n < 4; ++n) {
        float4 o;
        o.x = h[n * 4 + 0] * x0.x + h[n * 4 + 1] * x1.x + h[n * 4 + 2] * x2.x + h[n * 4 + 3] * x3.x;
        o.y = h[n * 4 + 0] * x0.y + h[n * 4 + 1] * x1.y + h[n * 4 + 2] * x2.y + h[n * 4 + 3] * x3.y;
        o.z = h[n * 4 + 0] * x0.z + h[n * 4 + 1] * x1.z + h[n * 4 + 2] * x2.z + h[n * 4 + 3] * x3.z;
        o.w = h[n * 4 + 0] * x0.w + h[n * 4 + 1] * x1.w + h[n * 4 + 2] * x2.w + h[n * 4 + 3] * x3.w;
        op[n * C] = o;
    }
}

extern "C" void kernel_launch(void* const* d_in, const int* in_sizes, int n_in,
                              void* d_out, int out_size, void* d_ws, size_t ws_size,
                              hipStream_t stream) {
    const float* x = (const float*)d_in[0];
    const float* H_raw = (const float*)d_in[1];
    float* out = (float*)d_out;
    float* H = (float*)d_ws;  // 16 floats of scratch

    sinkhorn_k<<<1, 64, 0, stream>>>(H_raw, H);

    // in_sizes[0] = B*T*n*D total floats; each thread covers 16 floats
    // (4 streams x float4) of input and the same of output.
    int n_items = in_sizes[0] / (N_STREAMS * 4);  // = BT * D/4 = 4,194,304
    int blocks = (n_items + 255) / 256;           // = 16384
    mix_k<<<blocks, 256, 0, stream>>>(x, H, out, n_items);
}